// Round 5
// baseline (130.168 us; speedup 1.0000x reference)
//
#include <hip/hip_runtime.h>

#define N_POST 50000
#define N_IN   17400
#define NNZ_E  1000000
#define T_DIM  64
#define R_DIM  5
#define NT_DIM 10

#define BROWS  256                                  // rows per bucket
#define NBUCK  ((N_POST + BROWS - 1) / BROWS)       // 196
#define EPB    4096                                 // edges per split block
#define NBLK1  ((NNZ_E + EPB - 1) / EPB)            // 245

#define TRANS_BLOCKS ((N_IN * T_DIM + 255) / 256)   // 4350

// ---- transpose x -> xT + zero bucket hist ----
__global__ void k_trans_zero(const float* __restrict__ x, float* __restrict__ xT,
                             int* __restrict__ bhist) {
    int b = blockIdx.x;
    if (b < TRANS_BLOCKS) {
        int tid = b * 256 + threadIdx.x;
        if (tid < N_IN * T_DIM) {
            int col = tid >> 6, t = tid & 63;
            xT[tid] = x[t * N_IN + col];
        }
    } else {
        if (threadIdx.x < NBUCK) bhist[threadIdx.x] = 0;
    }
}

// ---- coarse bucket histogram ----
__global__ __launch_bounds__(256) void k_bhist(const int2* __restrict__ idx2,
                                               int* __restrict__ bhist) {
    __shared__ int lh[NBUCK];
    int t = threadIdx.x;
    for (int i = t; i < NBUCK; i += 256) lh[i] = 0;
    __syncthreads();
    int base = blockIdx.x * EPB;
    int end = min(base + EPB, NNZ_E);
    for (int i = base + t; i < end; i += 256)
        atomicAdd(&lh[(unsigned)idx2[i].x >> 8], 1);
    __syncthreads();
    for (int i = t; i < NBUCK; i += 256)
        if (lh[i]) atomicAdd(&bhist[i], lh[i]);
}

// ---- tiny scan over buckets ----
__global__ void k_bscan(const int* __restrict__ bhist, int* __restrict__ bbase,
                        int* __restrict__ gcur, int* __restrict__ row_start) {
    __shared__ int buf[256];
    int t = threadIdx.x;
    int v = (t < NBUCK) ? bhist[t] : 0;
    buf[t] = v;
    __syncthreads();
    for (int off = 1; off < 256; off <<= 1) {
        int u = (t >= off) ? buf[t - off] : 0;
        __syncthreads();
        buf[t] += u;
        __syncthreads();
    }
    if (t <= NBUCK) bbase[t] = buf[t] - v;
    if (t < NBUCK)  gcur[t] = buf[t] - v;
    if (t == 0) row_start[N_POST] = NNZ_E;
}

// ---- pass 1: block-local counting sort by bucket, bucket-major coalesced flush ----
// rec1 record: x = col(15b) | sid<<15 (4b) | row_low<<19 (8b) ; y = weight bits
__global__ __launch_bounds__(256) void k_split(const int2* __restrict__ idx2,
                                               const float* __restrict__ iw,
                                               const int* __restrict__ sid,
                                               int* __restrict__ gcur,
                                               uint2* __restrict__ rec1) {
    __shared__ uint2 lsrc[EPB];
    __shared__ uint2 ldst[EPB];
    __shared__ unsigned char bsrc[EPB];
    __shared__ unsigned char bdst[EPB];
    __shared__ int lhist[256];
    __shared__ int lsc[256];
    __shared__ int lbase[256];
    __shared__ int lcur[256];
    __shared__ int gbase[NBUCK];
    int t = threadIdx.x;
    lhist[t] = 0;
    __syncthreads();
    int base = blockIdx.x * EPB;
    int n = min(EPB, NNZ_E - base);
    for (int i = t; i < n; i += 256) {
        int2 rc = idx2[base + i];
        unsigned b = (unsigned)rc.x >> 8;
        unsigned x = (unsigned)rc.y | ((unsigned)sid[base + i] << 15)
                   | ((unsigned)(rc.x & 255) << 19);
        lsrc[i] = make_uint2(x, __float_as_uint(iw[base + i]));
        bsrc[i] = (unsigned char)b;
        atomicAdd(&lhist[b], 1);
    }
    __syncthreads();
    int v = lhist[t];
    lsc[t] = v;
    __syncthreads();
    for (int off = 1; off < 256; off <<= 1) {
        int u = (t >= off) ? lsc[t - off] : 0;
        __syncthreads();
        lsc[t] += u;
        __syncthreads();
    }
    int excl = lsc[t] - v;
    lbase[t] = excl;
    lcur[t] = excl;
    if (t < NBUCK && v > 0) gbase[t] = atomicAdd(&gcur[t], v);
    __syncthreads();
    for (int i = t; i < n; i += 256) {
        int b = bsrc[i];
        int pos = atomicAdd(&lcur[b], 1);
        ldst[pos] = lsrc[i];
        bdst[pos] = (unsigned char)b;
    }
    __syncthreads();
    for (int i = t; i < n; i += 256) {
        int b = bdst[i];
        rec1[gbase[b] + (i - lbase[b])] = ldst[i];
    }
}

// ---- pass 2: per-bucket fine sort by row; pre-scales weights into 24B records ----
// rec record (3 x uint2): {col<<6, w*f0} {w*f1, w*f2} {w*f3, w*f4}
__global__ __launch_bounds__(256) void k_fine(const uint2* __restrict__ rec1,
                                              const int* __restrict__ bbase,
                                              const float* __restrict__ S,
                                              uint2* __restrict__ rec,
                                              int* __restrict__ row_start) {
    __shared__ int lhist[BROWS];
    __shared__ int lsc[BROWS];
    __shared__ int lcur[BROWS];
    __shared__ float s_S[NT_DIM * R_DIM];
    int t = threadIdx.x;
    if (t < NT_DIM * R_DIM) s_S[t] = S[t];
    int b = blockIdx.x;
    int s0 = bbase[b], s1 = bbase[b + 1];
    lhist[t] = 0;
    __syncthreads();
    for (int i = s0 + t; i < s1; i += 256)
        atomicAdd(&lhist[(rec1[i].x >> 19) & 255], 1);
    __syncthreads();
    int v = lhist[t];
    lsc[t] = v;
    __syncthreads();
    for (int off = 1; off < 256; off <<= 1) {
        int u = (t >= off) ? lsc[t - off] : 0;
        __syncthreads();
        lsc[t] += u;
        __syncthreads();
    }
    int excl = lsc[t] - v;
    int p = b * BROWS + t;
    if (p < N_POST) row_start[p] = s0 + excl;
    lcur[t] = excl;
    __syncthreads();
    for (int i = s0 + t; i < s1; i += 256) {
        uint2 rc = rec1[i];
        int r = (rc.x >> 19) & 255;
        int pos = atomicAdd(&lcur[r], 1);
        unsigned col = rc.x & 0x7FFF;
        const float* f = &s_S[((rc.x >> 15) & 0xF) * R_DIM];
        float w = __uint_as_float(rc.y);
        uint2* d = rec + (size_t)(s0 + pos) * 3;
        d[0] = make_uint2(col << 6, __float_as_uint(w * f[0]));
        d[1] = make_uint2(__float_as_uint(w * f[1]), __float_as_uint(w * f[2]));
        d[2] = make_uint2(__float_as_uint(w * f[3]), __float_as_uint(w * f[4]));
    }
}

#define FMAE(A, B, C, xv)                                \
    do {                                                 \
        a0 += (xv) * __uint_as_float((A).y);             \
        a1 += (xv) * __uint_as_float((B).x);             \
        a2 += (xv) * __uint_as_float((B).y);             \
        a3 += (xv) * __uint_as_float((C).x);             \
        a4 += (xv) * __uint_as_float((C).y);             \
    } while (0)

// ---- phase2: 16 consecutive p per block; lane = t; 4-edge SW pipeline; no LDS in loop ----
__global__ __launch_bounds__(256) void k_phase2(
        const float* __restrict__ xT, const int* __restrict__ row_start,
        const uint2* __restrict__ rec, float* __restrict__ out) {
    __shared__ float o_lds[T_DIM * 81];
    int tid = threadIdx.x;
    int wave = tid >> 6, lane = tid & 63;
    #pragma unroll
    for (int k = 0; k < 4; ++k) {
        int p = blockIdx.x * 16 + wave * 4 + k;
        int i = row_start[p];
        int end = row_start[p + 1];
        int n = end - i;
        const uint2* rp = rec + (size_t)i * 3;
        float a0 = 0.f, a1 = 0.f, a2 = 0.f, a3 = 0.f, a4 = 0.f;
        int j = 0;
        if (n >= 4) {
            uint2 A0 = rp[0], B0 = rp[1], C0 = rp[2];
            uint2 A1 = rp[3], B1 = rp[4], C1 = rp[5];
            uint2 A2 = rp[6], B2 = rp[7], C2 = rp[8];
            uint2 A3 = rp[9], B3 = rp[10], C3 = rp[11];
            float x0 = xT[A0.x + lane], x1 = xT[A1.x + lane];
            float x2 = xT[A2.x + lane], x3 = xT[A3.x + lane];
            for (j = 4; j + 4 <= n; j += 4) {
                const uint2* q = rp + j * 3;
                uint2 D0 = q[0], E0 = q[1], F0 = q[2];
                uint2 D1 = q[3], E1 = q[4], F1 = q[5];
                uint2 D2 = q[6], E2 = q[7], F2 = q[8];
                uint2 D3 = q[9], E3 = q[10], F3 = q[11];
                float y0 = xT[D0.x + lane], y1 = xT[D1.x + lane];
                float y2 = xT[D2.x + lane], y3 = xT[D3.x + lane];
                FMAE(A0, B0, C0, x0);
                FMAE(A1, B1, C1, x1);
                FMAE(A2, B2, C2, x2);
                FMAE(A3, B3, C3, x3);
                A0 = D0; B0 = E0; C0 = F0;
                A1 = D1; B1 = E1; C1 = F1;
                A2 = D2; B2 = E2; C2 = F2;
                A3 = D3; B3 = E3; C3 = F3;
                x0 = y0; x1 = y1; x2 = y2; x3 = y3;
            }
            FMAE(A0, B0, C0, x0);
            FMAE(A1, B1, C1, x1);
            FMAE(A2, B2, C2, x2);
            FMAE(A3, B3, C3, x3);
        }
        for (; j < n; ++j) {
            const uint2* q = rp + j * 3;
            uint2 A = q[0], B = q[1], C = q[2];
            float xv = xT[A.x + lane];
            FMAE(A, B, C, xv);
        }
        float* d = &o_lds[lane * 81 + (wave * 4 + k) * 5];
        d[0] = a0; d[1] = a1; d[2] = a2; d[3] = a3; d[4] = a4;
    }
    __syncthreads();
    int base5 = blockIdx.x * 80;
    for (int i2 = tid; i2 < T_DIM * 80; i2 += 256) {
        int t = i2 / 80;
        int j = i2 - t * 80;
        out[(size_t)t * (N_POST * R_DIM) + base5 + j] = o_lds[t * 81 + j];
    }
}

extern "C" void kernel_launch(void* const* d_in, const int* in_sizes, int n_in,
                              void* d_out, int out_size, void* d_ws, size_t ws_size,
                              hipStream_t stream) {
    const float* inp  = (const float*)d_in[0];
    const int2*  idx2 = (const int2*)d_in[1];
    const float* iw   = (const float*)d_in[2];
    const float* S    = (const float*)d_in[3];
    const int*   sid  = (const int*)d_in[4];
    float* out = (float*)d_out;

    char* ws = (char*)d_ws;
    size_t off = 0;
    auto alloc = [&](size_t bytes) -> void* {
        void* p = ws + off;
        off += (bytes + 255) & ~(size_t)255;
        return p;
    };
    float* xT        = (float*)alloc((size_t)N_IN * T_DIM * 4);
    int*   bhist     = (int*)alloc((size_t)NBUCK * 4);
    int*   bbase     = (int*)alloc((size_t)(NBUCK + 1) * 4);
    int*   gcur      = (int*)alloc((size_t)NBUCK * 4);
    int*   row_start = (int*)alloc((size_t)(N_POST + 1) * 4);
    uint2* rec1      = (uint2*)alloc((size_t)NNZ_E * 8);
    uint2* rec       = (uint2*)alloc((size_t)NNZ_E * 24);

    k_trans_zero<<<TRANS_BLOCKS + 1, 256, 0, stream>>>(inp, xT, bhist);
    k_bhist<<<NBLK1, 256, 0, stream>>>(idx2, bhist);
    k_bscan<<<1, 256, 0, stream>>>(bhist, bbase, gcur, row_start);
    k_split<<<NBLK1, 256, 0, stream>>>(idx2, iw, sid, gcur, rec1);
    k_fine<<<NBUCK, 256, 0, stream>>>(rec1, bbase, S, rec, row_start);
    k_phase2<<<N_POST / 16, 256, 0, stream>>>(xT, row_start, rec, out);
}

// Round 6
// 115.326 us; speedup vs baseline: 1.1287x; 1.1287x over previous
//
#include <hip/hip_runtime.h>
#include <hip/hip_fp16.h>

#define N_POST 50000
#define N_IN   17400
#define NNZ_E  1000000
#define T_DIM  64
#define R_DIM  5
#define NT_DIM 10

#define BROWS  256                                  // rows per bucket
#define NBUCK  ((N_POST + BROWS - 1) / BROWS)       // 196
#define EPB    4096                                 // edges per split block
#define NBLK1  ((NNZ_E + EPB - 1) / EPB)            // 245

#define TRANS_BLOCKS ((N_IN * T_DIM + 255) / 256)   // 4350

static __device__ __forceinline__ unsigned pack2h(float a, float b) {
    __half2 h = __floats2half2_rn(a, b);
    return *reinterpret_cast<unsigned*>(&h);
}
static __device__ __forceinline__ float2 uph2(unsigned u) {
    __half2 h;
    *reinterpret_cast<unsigned*>(&h) = u;
    return __half22float2(h);
}

// ---- fused: transpose x -> xT  AND  coarse bucket histogram (bhist pre-zeroed) ----
__global__ __launch_bounds__(256) void k_trans_bhist(const float* __restrict__ x,
                                                     float* __restrict__ xT,
                                                     const int2* __restrict__ idx2,
                                                     int* __restrict__ bhist) {
    int b = blockIdx.x;
    if (b < TRANS_BLOCKS) {
        int tid = b * 256 + threadIdx.x;
        if (tid < N_IN * T_DIM) {
            int col = tid >> 6, t = tid & 63;
            xT[tid] = x[t * N_IN + col];
        }
        return;
    }
    __shared__ int lh[NBUCK];
    int t = threadIdx.x;
    for (int i = t; i < NBUCK; i += 256) lh[i] = 0;
    __syncthreads();
    int base = (b - TRANS_BLOCKS) * EPB;
    int end = min(base + EPB, NNZ_E);
    for (int i = base + t; i < end; i += 256)
        atomicAdd(&lh[(unsigned)idx2[i].x >> 8], 1);
    __syncthreads();
    for (int i = t; i < NBUCK; i += 256)
        if (lh[i]) atomicAdd(&bhist[i], lh[i]);
}

// ---- tiny scan over buckets ----
__global__ void k_bscan(const int* __restrict__ bhist, int* __restrict__ bbase,
                        int* __restrict__ gcur, int* __restrict__ row_start) {
    __shared__ int buf[256];
    int t = threadIdx.x;
    int v = (t < NBUCK) ? bhist[t] : 0;
    buf[t] = v;
    __syncthreads();
    for (int off = 1; off < 256; off <<= 1) {
        int u = (t >= off) ? buf[t - off] : 0;
        __syncthreads();
        buf[t] += u;
        __syncthreads();
    }
    if (t <= NBUCK) bbase[t] = buf[t] - v;
    if (t < NBUCK)  gcur[t] = buf[t] - v;
    if (t == 0) row_start[N_POST] = NNZ_E;
}

// ---- pass 1: block-local counting sort by bucket, bucket-major coalesced flush ----
// rec1 record: x = col(15b) | sid<<15 (4b) | row_low<<19 (8b) ; y = weight bits
__global__ __launch_bounds__(256) void k_split(const int2* __restrict__ idx2,
                                               const float* __restrict__ iw,
                                               const int* __restrict__ sid,
                                               int* __restrict__ gcur,
                                               uint2* __restrict__ rec1) {
    __shared__ uint2 lsrc[EPB];
    __shared__ uint2 ldst[EPB];
    __shared__ unsigned char bsrc[EPB];
    __shared__ unsigned char bdst[EPB];
    __shared__ int lhist[256];
    __shared__ int lsc[256];
    __shared__ int lbase[256];
    __shared__ int lcur[256];
    __shared__ int gbase[NBUCK];
    int t = threadIdx.x;
    lhist[t] = 0;
    __syncthreads();
    int base = blockIdx.x * EPB;
    int n = min(EPB, NNZ_E - base);
    for (int i = t; i < n; i += 256) {
        int2 rc = idx2[base + i];
        unsigned b = (unsigned)rc.x >> 8;
        unsigned x = (unsigned)rc.y | ((unsigned)sid[base + i] << 15)
                   | ((unsigned)(rc.x & 255) << 19);
        lsrc[i] = make_uint2(x, __float_as_uint(iw[base + i]));
        bsrc[i] = (unsigned char)b;
        atomicAdd(&lhist[b], 1);
    }
    __syncthreads();
    int v = lhist[t];
    lsc[t] = v;
    __syncthreads();
    for (int off = 1; off < 256; off <<= 1) {
        int u = (t >= off) ? lsc[t - off] : 0;
        __syncthreads();
        lsc[t] += u;
        __syncthreads();
    }
    int excl = lsc[t] - v;
    lbase[t] = excl;
    lcur[t] = excl;
    if (t < NBUCK && v > 0) gbase[t] = atomicAdd(&gcur[t], v);
    __syncthreads();
    for (int i = t; i < n; i += 256) {
        int b = bsrc[i];
        int pos = atomicAdd(&lcur[b], 1);
        ldst[pos] = lsrc[i];
        bdst[pos] = (unsigned char)b;
    }
    __syncthreads();
    for (int i = t; i < n; i += 256) {
        int b = bdst[i];
        rec1[gbase[b] + (i - lbase[b])] = ldst[i];
    }
}

// ---- pass 2: per-bucket fine sort by row; 16B fp16 pre-scaled records ----
// rec (uint4): { col*64, half2(wf0,wf1), half2(wf2,wf3), half2(wf4,0) }
__global__ __launch_bounds__(256) void k_fine(const uint2* __restrict__ rec1,
                                              const int* __restrict__ bbase,
                                              const float* __restrict__ S,
                                              uint4* __restrict__ rec,
                                              int* __restrict__ row_start) {
    __shared__ int lhist[BROWS];
    __shared__ int lsc[BROWS];
    __shared__ int lcur[BROWS];
    __shared__ float s_S[NT_DIM * R_DIM];
    int t = threadIdx.x;
    if (t < NT_DIM * R_DIM) s_S[t] = S[t];
    int b = blockIdx.x;
    int s0 = bbase[b], s1 = bbase[b + 1];
    lhist[t] = 0;
    __syncthreads();
    for (int i = s0 + t; i < s1; i += 256)
        atomicAdd(&lhist[(rec1[i].x >> 19) & 255], 1);
    __syncthreads();
    int v = lhist[t];
    lsc[t] = v;
    __syncthreads();
    for (int off = 1; off < 256; off <<= 1) {
        int u = (t >= off) ? lsc[t - off] : 0;
        __syncthreads();
        lsc[t] += u;
        __syncthreads();
    }
    int excl = lsc[t] - v;
    int p = b * BROWS + t;
    if (p < N_POST) row_start[p] = s0 + excl;
    lcur[t] = excl;
    __syncthreads();
    for (int i = s0 + t; i < s1; i += 256) {
        uint2 rc = rec1[i];
        int r = (rc.x >> 19) & 255;
        int pos = atomicAdd(&lcur[r], 1);
        unsigned col = rc.x & 0x7FFF;
        const float* f = &s_S[((rc.x >> 15) & 0xF) * R_DIM];
        float w = __uint_as_float(rc.y);
        uint4 r4;
        r4.x = col << 6;
        r4.y = pack2h(w * f[0], w * f[1]);
        r4.z = pack2h(w * f[2], w * f[3]);
        r4.w = pack2h(w * f[4], 0.f);
        rec[s0 + pos] = r4;
    }
}

#define FMAH(A, xv)                                      \
    do {                                                 \
        float2 f01_ = uph2((A).y);                       \
        float2 f23_ = uph2((A).z);                       \
        float2 f4_  = uph2((A).w);                       \
        a0 = fmaf((xv), f01_.x, a0);                     \
        a1 = fmaf((xv), f01_.y, a1);                     \
        a2 = fmaf((xv), f23_.x, a2);                     \
        a3 = fmaf((xv), f23_.y, a3);                     \
        a4 = fmaf((xv), f4_.x,  a4);                     \
    } while (0)

// ---- phase2: 16 consecutive p per block; lane = t; 4-edge SW pipeline; no LDS in loop ----
__global__ __launch_bounds__(256) void k_phase2(
        const float* __restrict__ xT, const int* __restrict__ row_start,
        const uint4* __restrict__ rec, float* __restrict__ out) {
    __shared__ float o_lds[T_DIM * 81];
    int tid = threadIdx.x;
    int wave = tid >> 6, lane = tid & 63;
    #pragma unroll
    for (int k = 0; k < 4; ++k) {
        int p = blockIdx.x * 16 + wave * 4 + k;
        int i = row_start[p];
        int end = row_start[p + 1];
        int n = end - i;
        const uint4* rp = rec + i;
        float a0 = 0.f, a1 = 0.f, a2 = 0.f, a3 = 0.f, a4 = 0.f;
        int j = 0;
        if (n >= 4) {
            uint4 A0 = rp[0], A1 = rp[1], A2 = rp[2], A3 = rp[3];
            float x0 = xT[A0.x + lane], x1 = xT[A1.x + lane];
            float x2 = xT[A2.x + lane], x3 = xT[A3.x + lane];
            for (j = 4; j + 4 <= n; j += 4) {
                const uint4* q = rp + j;
                uint4 D0 = q[0], D1 = q[1], D2 = q[2], D3 = q[3];
                float y0 = xT[D0.x + lane], y1 = xT[D1.x + lane];
                float y2 = xT[D2.x + lane], y3 = xT[D3.x + lane];
                FMAH(A0, x0);
                FMAH(A1, x1);
                FMAH(A2, x2);
                FMAH(A3, x3);
                A0 = D0; A1 = D1; A2 = D2; A3 = D3;
                x0 = y0; x1 = y1; x2 = y2; x3 = y3;
            }
            FMAH(A0, x0);
            FMAH(A1, x1);
            FMAH(A2, x2);
            FMAH(A3, x3);
        }
        for (; j < n; ++j) {
            uint4 A = rp[j];
            float xv = xT[A.x + lane];
            FMAH(A, xv);
        }
        float* d = &o_lds[lane * 81 + (wave * 4 + k) * 5];
        d[0] = a0; d[1] = a1; d[2] = a2; d[3] = a3; d[4] = a4;
    }
    __syncthreads();
    int base5 = blockIdx.x * 80;
    for (int i2 = tid; i2 < T_DIM * 80; i2 += 256) {
        int t = i2 / 80;
        int j = i2 - t * 80;
        out[(size_t)t * (N_POST * R_DIM) + base5 + j] = o_lds[t * 81 + j];
    }
}

extern "C" void kernel_launch(void* const* d_in, const int* in_sizes, int n_in,
                              void* d_out, int out_size, void* d_ws, size_t ws_size,
                              hipStream_t stream) {
    const float* inp  = (const float*)d_in[0];
    const int2*  idx2 = (const int2*)d_in[1];
    const float* iw   = (const float*)d_in[2];
    const float* S    = (const float*)d_in[3];
    const int*   sid  = (const int*)d_in[4];
    float* out = (float*)d_out;

    char* ws = (char*)d_ws;
    size_t off = 0;
    auto alloc = [&](size_t bytes) -> void* {
        void* p = ws + off;
        off += (bytes + 255) & ~(size_t)255;
        return p;
    };
    float* xT        = (float*)alloc((size_t)N_IN * T_DIM * 4);
    int*   bhist     = (int*)alloc((size_t)NBUCK * 4);
    int*   bbase     = (int*)alloc((size_t)(NBUCK + 1) * 4);
    int*   gcur      = (int*)alloc((size_t)NBUCK * 4);
    int*   row_start = (int*)alloc((size_t)(N_POST + 1) * 4);
    uint2* rec1      = (uint2*)alloc((size_t)NNZ_E * 8);
    uint4* rec       = (uint4*)alloc((size_t)NNZ_E * 16);

    hipMemsetAsync(bhist, 0, NBUCK * 4, stream);
    k_trans_bhist<<<TRANS_BLOCKS + NBLK1, 256, 0, stream>>>(inp, xT, idx2, bhist);
    k_bscan<<<1, 256, 0, stream>>>(bhist, bbase, gcur, row_start);
    k_split<<<NBLK1, 256, 0, stream>>>(idx2, iw, sid, gcur, rec1);
    k_fine<<<NBUCK, 256, 0, stream>>>(rec1, bbase, S, rec, row_start);
    k_phase2<<<N_POST / 16, 256, 0, stream>>>(xT, row_start, rec, out);
}

// Round 7
// 110.693 us; speedup vs baseline: 1.1759x; 1.0419x over previous
//
#include <hip/hip_runtime.h>
#include <hip/hip_fp16.h>

#define N_POST 50000
#define N_IN   17400
#define NNZ_E  1000000
#define T_DIM  64
#define R_DIM  5
#define NT_DIM 10

#define BROWS  256                                  // rows per bucket
#define NBUCK  ((N_POST + BROWS - 1) / BROWS)       // 196
#define EPB    4096                                 // edges per split block
#define NBLK1  ((NNZ_E + EPB - 1) / EPB)            // 245

#define TRANS_BLOCKS ((N_IN * T_DIM + 255) / 256)   // 4350

static __device__ __forceinline__ unsigned pack2h(float a, float b) {
    __half2 h = __floats2half2_rn(a, b);
    return *reinterpret_cast<unsigned*>(&h);
}
static __device__ __forceinline__ float2 uph2(unsigned u) {
    __half2 h;
    *reinterpret_cast<unsigned*>(&h) = u;
    return __half22float2(h);
}

// ---- fused: transpose x -> xT (fp16)  AND  coarse bucket histogram ----
__global__ __launch_bounds__(256) void k_trans_bhist(const float* __restrict__ x,
                                                     __half* __restrict__ xT,
                                                     const int2* __restrict__ idx2,
                                                     int* __restrict__ bhist) {
    int b = blockIdx.x;
    if (b < TRANS_BLOCKS) {
        int tid = b * 256 + threadIdx.x;
        if (tid < N_IN * T_DIM) {
            int col = tid >> 6, t = tid & 63;
            xT[tid] = __float2half(x[t * N_IN + col]);
        }
        return;
    }
    __shared__ int lh[NBUCK];
    int t = threadIdx.x;
    for (int i = t; i < NBUCK; i += 256) lh[i] = 0;
    __syncthreads();
    int base = (b - TRANS_BLOCKS) * EPB;
    int end = min(base + EPB, NNZ_E);
    for (int i = base + t; i < end; i += 256)
        atomicAdd(&lh[(unsigned)idx2[i].x >> 8], 1);
    __syncthreads();
    for (int i = t; i < NBUCK; i += 256)
        if (lh[i]) atomicAdd(&bhist[i], lh[i]);
}

// ---- tiny scan over buckets ----
__global__ void k_bscan(const int* __restrict__ bhist, int* __restrict__ bbase,
                        int* __restrict__ gcur, int* __restrict__ row_start) {
    __shared__ int buf[256];
    int t = threadIdx.x;
    int v = (t < NBUCK) ? bhist[t] : 0;
    buf[t] = v;
    __syncthreads();
    for (int off = 1; off < 256; off <<= 1) {
        int u = (t >= off) ? buf[t - off] : 0;
        __syncthreads();
        buf[t] += u;
        __syncthreads();
    }
    if (t <= NBUCK) bbase[t] = buf[t] - v;
    if (t < NBUCK)  gcur[t] = buf[t] - v;
    if (t == 0) row_start[N_POST] = NNZ_E;
}

// ---- pass 1: block-local counting sort by bucket, bucket-major coalesced flush ----
// rec1 record: x = col(15b) | sid<<15 (4b) | row_low<<19 (8b) ; y = weight bits
__global__ __launch_bounds__(256) void k_split(const int2* __restrict__ idx2,
                                               const float* __restrict__ iw,
                                               const int* __restrict__ sid,
                                               int* __restrict__ gcur,
                                               uint2* __restrict__ rec1) {
    __shared__ uint2 lsrc[EPB];
    __shared__ uint2 ldst[EPB];
    __shared__ unsigned char bsrc[EPB];
    __shared__ unsigned char bdst[EPB];
    __shared__ int lhist[256];
    __shared__ int lsc[256];
    __shared__ int lbase[256];
    __shared__ int lcur[256];
    __shared__ int gbase[NBUCK];
    int t = threadIdx.x;
    lhist[t] = 0;
    __syncthreads();
    int base = blockIdx.x * EPB;
    int n = min(EPB, NNZ_E - base);
    for (int i = t; i < n; i += 256) {
        int2 rc = idx2[base + i];
        unsigned b = (unsigned)rc.x >> 8;
        unsigned x = (unsigned)rc.y | ((unsigned)sid[base + i] << 15)
                   | ((unsigned)(rc.x & 255) << 19);
        lsrc[i] = make_uint2(x, __float_as_uint(iw[base + i]));
        bsrc[i] = (unsigned char)b;
        atomicAdd(&lhist[b], 1);
    }
    __syncthreads();
    int v = lhist[t];
    lsc[t] = v;
    __syncthreads();
    for (int off = 1; off < 256; off <<= 1) {
        int u = (t >= off) ? lsc[t - off] : 0;
        __syncthreads();
        lsc[t] += u;
        __syncthreads();
    }
    int excl = lsc[t] - v;
    lbase[t] = excl;
    lcur[t] = excl;
    if (t < NBUCK && v > 0) gbase[t] = atomicAdd(&gcur[t], v);
    __syncthreads();
    for (int i = t; i < n; i += 256) {
        int b = bsrc[i];
        int pos = atomicAdd(&lcur[b], 1);
        ldst[pos] = lsrc[i];
        bdst[pos] = (unsigned char)b;
    }
    __syncthreads();
    for (int i = t; i < n; i += 256) {
        int b = bdst[i];
        rec1[gbase[b] + (i - lbase[b])] = ldst[i];
    }
}

// ---- pass 2: per-bucket fine sort by row; 16B fp16 pre-scaled records ----
// rec (uint4): { col*64, half2(wf0,wf1), half2(wf2,wf3), half2(wf4,0) }
__global__ __launch_bounds__(256) void k_fine(const uint2* __restrict__ rec1,
                                              const int* __restrict__ bbase,
                                              const float* __restrict__ S,
                                              uint4* __restrict__ rec,
                                              int* __restrict__ row_start) {
    __shared__ int lhist[BROWS];
    __shared__ int lsc[BROWS];
    __shared__ int lcur[BROWS];
    __shared__ float s_S[NT_DIM * R_DIM];
    int t = threadIdx.x;
    if (t < NT_DIM * R_DIM) s_S[t] = S[t];
    int b = blockIdx.x;
    int s0 = bbase[b], s1 = bbase[b + 1];
    lhist[t] = 0;
    __syncthreads();
    for (int i = s0 + t; i < s1; i += 256)
        atomicAdd(&lhist[(rec1[i].x >> 19) & 255], 1);
    __syncthreads();
    int v = lhist[t];
    lsc[t] = v;
    __syncthreads();
    for (int off = 1; off < 256; off <<= 1) {
        int u = (t >= off) ? lsc[t - off] : 0;
        __syncthreads();
        lsc[t] += u;
        __syncthreads();
    }
    int excl = lsc[t] - v;
    int p = b * BROWS + t;
    if (p < N_POST) row_start[p] = s0 + excl;
    lcur[t] = excl;
    __syncthreads();
    for (int i = s0 + t; i < s1; i += 256) {
        uint2 rc = rec1[i];
        int r = (rc.x >> 19) & 255;
        int pos = atomicAdd(&lcur[r], 1);
        unsigned col = rc.x & 0x7FFF;
        const float* f = &s_S[((rc.x >> 15) & 0xF) * R_DIM];
        float w = __uint_as_float(rc.y);
        uint4 r4;
        r4.x = col << 6;
        r4.y = pack2h(w * f[0], w * f[1]);
        r4.z = pack2h(w * f[2], w * f[3]);
        r4.w = pack2h(w * f[4], 0.f);
        rec[s0 + pos] = r4;
    }
}

#define FMAH(A, xh)                                      \
    do {                                                 \
        float xv_ = __half2float(xh);                    \
        float2 f01_ = uph2((A).y);                       \
        float2 f23_ = uph2((A).z);                       \
        float2 f4_  = uph2((A).w);                       \
        a0 = fmaf(xv_, f01_.x, a0);                      \
        a1 = fmaf(xv_, f01_.y, a1);                      \
        a2 = fmaf(xv_, f23_.x, a2);                      \
        a3 = fmaf(xv_, f23_.y, a3);                      \
        a4 = fmaf(xv_, f4_.x,  a4);                      \
    } while (0)

// ---- phase2: 16 consecutive p per block; lane = t; 8-edge SW pipeline; fp16 xT ----
__global__ __launch_bounds__(256) void k_phase2(
        const __half* __restrict__ xT, const int* __restrict__ row_start,
        const uint4* __restrict__ rec, float* __restrict__ out) {
    __shared__ float o_lds[T_DIM * 81];
    int tid = threadIdx.x;
    int wave = tid >> 6, lane = tid & 63;
    #pragma unroll
    for (int k = 0; k < 4; ++k) {
        int p = blockIdx.x * 16 + wave * 4 + k;
        int i = row_start[p];
        int end = row_start[p + 1];
        int n = end - i;
        const uint4* rp = rec + i;
        float a0 = 0.f, a1 = 0.f, a2 = 0.f, a3 = 0.f, a4 = 0.f;
        int j = 0;
        if (n >= 8) {
            uint4 A0 = rp[0], A1 = rp[1], A2 = rp[2], A3 = rp[3];
            uint4 A4 = rp[4], A5 = rp[5], A6 = rp[6], A7 = rp[7];
            __half x0 = xT[A0.x + lane], x1 = xT[A1.x + lane];
            __half x2 = xT[A2.x + lane], x3 = xT[A3.x + lane];
            __half x4 = xT[A4.x + lane], x5 = xT[A5.x + lane];
            __half x6 = xT[A6.x + lane], x7 = xT[A7.x + lane];
            for (j = 8; j + 8 <= n; j += 8) {
                const uint4* q = rp + j;
                uint4 D0 = q[0], D1 = q[1], D2 = q[2], D3 = q[3];
                uint4 D4 = q[4], D5 = q[5], D6 = q[6], D7 = q[7];
                __half y0 = xT[D0.x + lane], y1 = xT[D1.x + lane];
                __half y2 = xT[D2.x + lane], y3 = xT[D3.x + lane];
                __half y4 = xT[D4.x + lane], y5 = xT[D5.x + lane];
                __half y6 = xT[D6.x + lane], y7 = xT[D7.x + lane];
                FMAH(A0, x0); FMAH(A1, x1); FMAH(A2, x2); FMAH(A3, x3);
                FMAH(A4, x4); FMAH(A5, x5); FMAH(A6, x6); FMAH(A7, x7);
                A0 = D0; A1 = D1; A2 = D2; A3 = D3;
                A4 = D4; A5 = D5; A6 = D6; A7 = D7;
                x0 = y0; x1 = y1; x2 = y2; x3 = y3;
                x4 = y4; x5 = y5; x6 = y6; x7 = y7;
            }
            FMAH(A0, x0); FMAH(A1, x1); FMAH(A2, x2); FMAH(A3, x3);
            FMAH(A4, x4); FMAH(A5, x5); FMAH(A6, x6); FMAH(A7, x7);
        }
        if (j + 4 <= n) {
            uint4 A0 = rp[j], A1 = rp[j + 1], A2 = rp[j + 2], A3 = rp[j + 3];
            __half x0 = xT[A0.x + lane], x1 = xT[A1.x + lane];
            __half x2 = xT[A2.x + lane], x3 = xT[A3.x + lane];
            FMAH(A0, x0); FMAH(A1, x1); FMAH(A2, x2); FMAH(A3, x3);
            j += 4;
        }
        for (; j < n; ++j) {
            uint4 A = rp[j];
            __half xv = xT[A.x + lane];
            FMAH(A, xv);
        }
        float* d = &o_lds[lane * 81 + (wave * 4 + k) * 5];
        d[0] = a0; d[1] = a1; d[2] = a2; d[3] = a3; d[4] = a4;
    }
    __syncthreads();
    int base5 = blockIdx.x * 80;
    for (int i2 = tid; i2 < T_DIM * 80; i2 += 256) {
        int t = i2 / 80;
        int j = i2 - t * 80;
        out[(size_t)t * (N_POST * R_DIM) + base5 + j] = o_lds[t * 81 + j];
    }
}

extern "C" void kernel_launch(void* const* d_in, const int* in_sizes, int n_in,
                              void* d_out, int out_size, void* d_ws, size_t ws_size,
                              hipStream_t stream) {
    const float* inp  = (const float*)d_in[0];
    const int2*  idx2 = (const int2*)d_in[1];
    const float* iw   = (const float*)d_in[2];
    const float* S    = (const float*)d_in[3];
    const int*   sid  = (const int*)d_in[4];
    float* out = (float*)d_out;

    char* ws = (char*)d_ws;
    size_t off = 0;
    auto alloc = [&](size_t bytes) -> void* {
        void* p = ws + off;
        off += (bytes + 255) & ~(size_t)255;
        return p;
    };
    __half* xT       = (__half*)alloc((size_t)N_IN * T_DIM * 2);
    int*   bhist     = (int*)alloc((size_t)NBUCK * 4);
    int*   bbase     = (int*)alloc((size_t)(NBUCK + 1) * 4);
    int*   gcur      = (int*)alloc((size_t)NBUCK * 4);
    int*   row_start = (int*)alloc((size_t)(N_POST + 1) * 4);
    uint2* rec1      = (uint2*)alloc((size_t)NNZ_E * 8);
    uint4* rec       = (uint4*)alloc((size_t)NNZ_E * 16);

    hipMemsetAsync(bhist, 0, NBUCK * 4, stream);
    k_trans_bhist<<<TRANS_BLOCKS + NBLK1, 256, 0, stream>>>(inp, xT, idx2, bhist);
    k_bscan<<<1, 256, 0, stream>>>(bhist, bbase, gcur, row_start);
    k_split<<<NBLK1, 256, 0, stream>>>(idx2, iw, sid, gcur, rec1);
    k_fine<<<NBUCK, 256, 0, stream>>>(rec1, bbase, S, rec, row_start);
    k_phase2<<<N_POST / 16, 256, 0, stream>>>(xT, row_start, rec, out);
}

// Round 8
// 99.640 us; speedup vs baseline: 1.3064x; 1.1109x over previous
//
#include <hip/hip_runtime.h>
#include <hip/hip_fp16.h>

#define N_POST 50000
#define N_IN   17400
#define NNZ_E  1000000
#define T_DIM  64
#define R_DIM  5
#define NT_DIM 10

#define BROWS  256                                  // rows per bucket
#define NBUCK  ((N_POST + BROWS - 1) / BROWS)       // 196
#define EPB    4096                                 // edges per split block
#define NBLK1  ((NNZ_E + EPB - 1) / EPB)            // 245
#define PADCAP 1024                                 // pad allowance per bucket (>256*3)

#define TRANS_BLOCKS ((N_IN * T_DIM + 255) / 256)   // 4350

static __device__ __forceinline__ unsigned pack2h(float a, float b) {
    __half2 h = __floats2half2_rn(a, b);
    return *reinterpret_cast<unsigned*>(&h);
}
static __device__ __forceinline__ float2 uph2(unsigned u) {
    __half2 h;
    *reinterpret_cast<unsigned*>(&h) = u;
    return __half22float2(h);
}

// ---- fused: transpose x -> xT (fp16)  AND  coarse bucket histogram ----
__global__ __launch_bounds__(256) void k_trans_bhist(const float* __restrict__ x,
                                                     __half* __restrict__ xT,
                                                     const int2* __restrict__ idx2,
                                                     int* __restrict__ bhist) {
    int b = blockIdx.x;
    if (b < TRANS_BLOCKS) {
        int tid = b * 256 + threadIdx.x;
        if (tid < N_IN * T_DIM) {
            int col = tid >> 6, t = tid & 63;
            xT[tid] = __float2half(x[t * N_IN + col]);
        }
        return;
    }
    __shared__ int lh[NBUCK];
    int t = threadIdx.x;
    for (int i = t; i < NBUCK; i += 256) lh[i] = 0;
    __syncthreads();
    int base = (b - TRANS_BLOCKS) * EPB;
    int end = min(base + EPB, NNZ_E);
    for (int i = base + t; i < end; i += 256)
        atomicAdd(&lh[(unsigned)idx2[i].x >> 8], 1);
    __syncthreads();
    for (int i = t; i < NBUCK; i += 256)
        if (lh[i]) atomicAdd(&bhist[i], lh[i]);
}

// ---- tiny scan over buckets ----
__global__ void k_bscan(const int* __restrict__ bhist, int* __restrict__ bbase,
                        int* __restrict__ gcur) {
    __shared__ int buf[256];
    int t = threadIdx.x;
    int v = (t < NBUCK) ? bhist[t] : 0;
    buf[t] = v;
    __syncthreads();
    for (int off = 1; off < 256; off <<= 1) {
        int u = (t >= off) ? buf[t - off] : 0;
        __syncthreads();
        buf[t] += u;
        __syncthreads();
    }
    if (t <= NBUCK) bbase[t] = buf[t] - v;
    if (t < NBUCK)  gcur[t] = buf[t] - v;
}

// ---- pass 1: block-local counting sort by bucket, bucket-major coalesced flush ----
// rec1 record: x = col(15b) | sid<<15 (4b) | row_low<<19 (8b) ; y = weight bits
__global__ __launch_bounds__(256) void k_split(const int2* __restrict__ idx2,
                                               const float* __restrict__ iw,
                                               const int* __restrict__ sid,
                                               int* __restrict__ gcur,
                                               uint2* __restrict__ rec1) {
    __shared__ uint2 lsrc[EPB];
    __shared__ uint2 ldst[EPB];
    __shared__ unsigned char bsrc[EPB];
    __shared__ unsigned char bdst[EPB];
    __shared__ int lhist[256];
    __shared__ int lsc[256];
    __shared__ int lbase[256];
    __shared__ int lcur[256];
    __shared__ int gbase[NBUCK];
    int t = threadIdx.x;
    lhist[t] = 0;
    __syncthreads();
    int base = blockIdx.x * EPB;
    int n = min(EPB, NNZ_E - base);
    for (int i = t; i < n; i += 256) {
        int2 rc = idx2[base + i];
        unsigned b = (unsigned)rc.x >> 8;
        unsigned x = (unsigned)rc.y | ((unsigned)sid[base + i] << 15)
                   | ((unsigned)(rc.x & 255) << 19);
        lsrc[i] = make_uint2(x, __float_as_uint(iw[base + i]));
        bsrc[i] = (unsigned char)b;
        atomicAdd(&lhist[b], 1);
    }
    __syncthreads();
    int v = lhist[t];
    lsc[t] = v;
    __syncthreads();
    for (int off = 1; off < 256; off <<= 1) {
        int u = (t >= off) ? lsc[t - off] : 0;
        __syncthreads();
        lsc[t] += u;
        __syncthreads();
    }
    int excl = lsc[t] - v;
    lbase[t] = excl;
    lcur[t] = excl;
    if (t < NBUCK && v > 0) gbase[t] = atomicAdd(&gcur[t], v);
    __syncthreads();
    for (int i = t; i < n; i += 256) {
        int b = bsrc[i];
        int pos = atomicAdd(&lcur[b], 1);
        ldst[pos] = lsrc[i];
        bdst[pos] = (unsigned char)b;
    }
    __syncthreads();
    for (int i = t; i < n; i += 256) {
        int b = bdst[i];
        rec1[gbase[b] + (i - lbase[b])] = ldst[i];
    }
}

// ---- pass 2: per-bucket fine sort by row; 16B fp16 pre-scaled records,
//      row lists PADDED to multiples of 4 with zero records ----
__global__ __launch_bounds__(256) void k_fine(const uint2* __restrict__ rec1,
                                              const int* __restrict__ bbase,
                                              const float* __restrict__ S,
                                              uint4* __restrict__ rec,
                                              int* __restrict__ rstart,
                                              int* __restrict__ plen) {
    __shared__ int lhist[BROWS];
    __shared__ int lsc[BROWS];
    __shared__ int lcur[BROWS];
    __shared__ float s_S[NT_DIM * R_DIM];
    int t = threadIdx.x;
    if (t < NT_DIM * R_DIM) s_S[t] = S[t];
    int b = blockIdx.x;
    int s0 = bbase[b], s1 = bbase[b + 1];
    int pbase = s0 + b * PADCAP;
    lhist[t] = 0;
    __syncthreads();
    for (int i = s0 + t; i < s1; i += 256)
        atomicAdd(&lhist[(rec1[i].x >> 19) & 255], 1);
    __syncthreads();
    int v = lhist[t];
    int vp = (v + 3) & ~3;
    lsc[t] = vp;
    __syncthreads();
    for (int off = 1; off < 256; off <<= 1) {
        int u = (t >= off) ? lsc[t - off] : 0;
        __syncthreads();
        lsc[t] += u;
        __syncthreads();
    }
    int exclp = lsc[t] - vp;
    int p = b * BROWS + t;
    if (p < N_POST) { rstart[p] = pbase + exclp; plen[p] = vp; }
    lcur[t] = exclp;
    __syncthreads();
    for (int i = s0 + t; i < s1; i += 256) {
        uint2 rc = rec1[i];
        int r = (rc.x >> 19) & 255;
        int pos = atomicAdd(&lcur[r], 1);
        unsigned col = rc.x & 0x7FFF;
        const float* f = &s_S[((rc.x >> 15) & 0xF) * R_DIM];
        float w = __uint_as_float(rc.y);
        uint4 r4;
        r4.x = col << 6;
        r4.y = pack2h(w * f[0], w * f[1]);
        r4.z = pack2h(w * f[2], w * f[3]);
        r4.w = pack2h(w * f[4], 0.f);
        rec[pbase + pos] = r4;
    }
    // zero-pad this thread's row up to the multiple of 4
    for (int u = v; u < vp; ++u)
        rec[pbase + exclp + u] = make_uint4(0, 0, 0, 0);
}

// FMA of one record into a named accumulator set
#define FMA5(A, xh, c0, c1, c2, c3, c4)                  \
    do {                                                 \
        float xv_ = __half2float(xh);                    \
        float2 f01_ = uph2((A).y);                       \
        float2 f23_ = uph2((A).z);                       \
        float2 f4_  = uph2((A).w);                       \
        c0 = fmaf(xv_, f01_.x, c0);                      \
        c1 = fmaf(xv_, f01_.y, c1);                      \
        c2 = fmaf(xv_, f23_.x, c2);                      \
        c3 = fmaf(xv_, f23_.y, c3);                      \
        c4 = fmaf(xv_, f4_.x,  c4);                      \
    } while (0)

// ---- phase2: 16 rows/block; each wave runs TWO independent row-chains (pairs),
//      4-deep pipeline each; rows pre-padded to multiples of 4 (no tails) ----
__global__ __launch_bounds__(256) void k_phase2(
        const __half* __restrict__ xT, const int* __restrict__ rstart,
        const int* __restrict__ plen, const uint4* __restrict__ rec,
        float* __restrict__ out) {
    __shared__ float o_lds[T_DIM * 81];
    int tid = threadIdx.x;
    int wave = tid >> 6, lane = tid & 63;
    #pragma unroll
    for (int h = 0; h < 2; ++h) {
        int pa = blockIdx.x * 16 + wave * 4 + h * 2;
        int pb = pa + 1;
        int ia = __builtin_amdgcn_readfirstlane(rstart[pa]);
        int na = __builtin_amdgcn_readfirstlane(plen[pa]);
        int ib = __builtin_amdgcn_readfirstlane(rstart[pb]);
        int nb = __builtin_amdgcn_readfirstlane(plen[pb]);
        const uint4* ra = rec + ia;
        const uint4* rb = rec + ib;
        float aa0 = 0.f, aa1 = 0.f, aa2 = 0.f, aa3 = 0.f, aa4 = 0.f;
        float ab0 = 0.f, ab1 = 0.f, ab2 = 0.f, ab3 = 0.f, ab4 = 0.f;
        uint4 A0, A1, A2, A3, B0, B1, B2, B3;
        __half xa0, xa1, xa2, xa3, xb0, xb1, xb2, xb3;
        int ja = 0, jb = 0;
        if (na) {
            A0 = ra[0]; A1 = ra[1]; A2 = ra[2]; A3 = ra[3];
            xa0 = xT[A0.x + lane]; xa1 = xT[A1.x + lane];
            xa2 = xT[A2.x + lane]; xa3 = xT[A3.x + lane];
            ja = 4;
        }
        if (nb) {
            B0 = rb[0]; B1 = rb[1]; B2 = rb[2]; B3 = rb[3];
            xb0 = xT[B0.x + lane]; xb1 = xT[B1.x + lane];
            xb2 = xT[B2.x + lane]; xb3 = xT[B3.x + lane];
            jb = 4;
        }
        while (ja < na && jb < nb) {            // both chains live
            const uint4* qa = ra + ja;
            const uint4* qb = rb + jb;
            uint4 D0 = qa[0], D1 = qa[1], D2 = qa[2], D3 = qa[3];
            uint4 E0 = qb[0], E1 = qb[1], E2 = qb[2], E3 = qb[3];
            __half ya0 = xT[D0.x + lane], ya1 = xT[D1.x + lane];
            __half ya2 = xT[D2.x + lane], ya3 = xT[D3.x + lane];
            __half yb0 = xT[E0.x + lane], yb1 = xT[E1.x + lane];
            __half yb2 = xT[E2.x + lane], yb3 = xT[E3.x + lane];
            FMA5(A0, xa0, aa0, aa1, aa2, aa3, aa4);
            FMA5(A1, xa1, aa0, aa1, aa2, aa3, aa4);
            FMA5(A2, xa2, aa0, aa1, aa2, aa3, aa4);
            FMA5(A3, xa3, aa0, aa1, aa2, aa3, aa4);
            FMA5(B0, xb0, ab0, ab1, ab2, ab3, ab4);
            FMA5(B1, xb1, ab0, ab1, ab2, ab3, ab4);
            FMA5(B2, xb2, ab0, ab1, ab2, ab3, ab4);
            FMA5(B3, xb3, ab0, ab1, ab2, ab3, ab4);
            A0 = D0; A1 = D1; A2 = D2; A3 = D3;
            B0 = E0; B1 = E1; B2 = E2; B3 = E3;
            xa0 = ya0; xa1 = ya1; xa2 = ya2; xa3 = ya3;
            xb0 = yb0; xb1 = yb1; xb2 = yb2; xb3 = yb3;
            ja += 4; jb += 4;
        }
        while (ja < na) {                       // drain chain A
            const uint4* qa = ra + ja;
            uint4 D0 = qa[0], D1 = qa[1], D2 = qa[2], D3 = qa[3];
            __half ya0 = xT[D0.x + lane], ya1 = xT[D1.x + lane];
            __half ya2 = xT[D2.x + lane], ya3 = xT[D3.x + lane];
            FMA5(A0, xa0, aa0, aa1, aa2, aa3, aa4);
            FMA5(A1, xa1, aa0, aa1, aa2, aa3, aa4);
            FMA5(A2, xa2, aa0, aa1, aa2, aa3, aa4);
            FMA5(A3, xa3, aa0, aa1, aa2, aa3, aa4);
            A0 = D0; A1 = D1; A2 = D2; A3 = D3;
            xa0 = ya0; xa1 = ya1; xa2 = ya2; xa3 = ya3;
            ja += 4;
        }
        while (jb < nb) {                       // drain chain B
            const uint4* qb = rb + jb;
            uint4 E0 = qb[0], E1 = qb[1], E2 = qb[2], E3 = qb[3];
            __half yb0 = xT[E0.x + lane], yb1 = xT[E1.x + lane];
            __half yb2 = xT[E2.x + lane], yb3 = xT[E3.x + lane];
            FMA5(B0, xb0, ab0, ab1, ab2, ab3, ab4);
            FMA5(B1, xb1, ab0, ab1, ab2, ab3, ab4);
            FMA5(B2, xb2, ab0, ab1, ab2, ab3, ab4);
            FMA5(B3, xb3, ab0, ab1, ab2, ab3, ab4);
            B0 = E0; B1 = E1; B2 = E2; B3 = E3;
            xb0 = yb0; xb1 = yb1; xb2 = yb2; xb3 = yb3;
            jb += 4;
        }
        if (na) {                               // retire pending A group
            FMA5(A0, xa0, aa0, aa1, aa2, aa3, aa4);
            FMA5(A1, xa1, aa0, aa1, aa2, aa3, aa4);
            FMA5(A2, xa2, aa0, aa1, aa2, aa3, aa4);
            FMA5(A3, xa3, aa0, aa1, aa2, aa3, aa4);
        }
        if (nb) {                               // retire pending B group
            FMA5(B0, xb0, ab0, ab1, ab2, ab3, ab4);
            FMA5(B1, xb1, ab0, ab1, ab2, ab3, ab4);
            FMA5(B2, xb2, ab0, ab1, ab2, ab3, ab4);
            FMA5(B3, xb3, ab0, ab1, ab2, ab3, ab4);
        }
        float* da = &o_lds[lane * 81 + (wave * 4 + h * 2) * 5];
        da[0] = aa0; da[1] = aa1; da[2] = aa2; da[3] = aa3; da[4] = aa4;
        float* db = &o_lds[lane * 81 + (wave * 4 + h * 2 + 1) * 5];
        db[0] = ab0; db[1] = ab1; db[2] = ab2; db[3] = ab3; db[4] = ab4;
    }
    __syncthreads();
    int base5 = blockIdx.x * 80;
    for (int i2 = tid; i2 < T_DIM * 80; i2 += 256) {
        int t = i2 / 80;
        int j = i2 - t * 80;
        out[(size_t)t * (N_POST * R_DIM) + base5 + j] = o_lds[t * 81 + j];
    }
}

extern "C" void kernel_launch(void* const* d_in, const int* in_sizes, int n_in,
                              void* d_out, int out_size, void* d_ws, size_t ws_size,
                              hipStream_t stream) {
    const float* inp  = (const float*)d_in[0];
    const int2*  idx2 = (const int2*)d_in[1];
    const float* iw   = (const float*)d_in[2];
    const float* S    = (const float*)d_in[3];
    const int*   sid  = (const int*)d_in[4];
    float* out = (float*)d_out;

    char* ws = (char*)d_ws;
    size_t off = 0;
    auto alloc = [&](size_t bytes) -> void* {
        void* p = ws + off;
        off += (bytes + 255) & ~(size_t)255;
        return p;
    };
    __half* xT       = (__half*)alloc((size_t)N_IN * T_DIM * 2);
    int*   bhist     = (int*)alloc((size_t)NBUCK * 4);
    int*   bbase     = (int*)alloc((size_t)(NBUCK + 1) * 4);
    int*   gcur      = (int*)alloc((size_t)NBUCK * 4);
    int*   rstart    = (int*)alloc((size_t)N_POST * 4);
    int*   plen      = (int*)alloc((size_t)N_POST * 4);
    uint2* rec1      = (uint2*)alloc((size_t)NNZ_E * 8);
    uint4* rec       = (uint4*)alloc(((size_t)NNZ_E + (size_t)NBUCK * PADCAP) * 16);

    hipMemsetAsync(bhist, 0, NBUCK * 4, stream);
    k_trans_bhist<<<TRANS_BLOCKS + NBLK1, 256, 0, stream>>>(inp, xT, idx2, bhist);
    k_bscan<<<1, 256, 0, stream>>>(bhist, bbase, gcur);
    k_split<<<NBLK1, 256, 0, stream>>>(idx2, iw, sid, gcur, rec1);
    k_fine<<<NBUCK, 256, 0, stream>>>(rec1, bbase, S, rec, rstart, plen);
    k_phase2<<<N_POST / 16, 256, 0, stream>>>(xT, rstart, plen, rec, out);
}

// Round 9
// 98.817 us; speedup vs baseline: 1.3173x; 1.0083x over previous
//
#include <hip/hip_runtime.h>
#include <hip/hip_fp16.h>

#define N_POST 50000
#define N_IN   17400
#define NNZ_E  1000000
#define T_DIM  64
#define R_DIM  5
#define NT_DIM 10

#define BROWS  256                                  // rows per bucket
#define NBUCK  ((N_POST + BROWS - 1) / BROWS)       // 196
#define EPB    2048                                 // edges per split block
#define NBLK1  ((NNZ_E + EPB - 1) / EPB)            // 489
#define HEPB   4096                                 // edges per hist block
#define NBLKH  ((NNZ_E + HEPB - 1) / HEPB)          // 245
#define PADCAP 1024                                 // pad allowance per bucket (>256*3)

#define TRANS_BLOCKS ((N_IN * T_DIM + 255) / 256)   // 4350

static __device__ __forceinline__ unsigned pack2h(float a, float b) {
    __half2 h = __floats2half2_rn(a, b);
    return *reinterpret_cast<unsigned*>(&h);
}
static __device__ __forceinline__ float2 uph2(unsigned u) {
    __half2 h;
    *reinterpret_cast<unsigned*>(&h) = u;
    return __half22float2(h);
}

// ---- fused: transpose x -> xT (fp16)  AND  coarse bucket histogram ----
__global__ __launch_bounds__(256) void k_trans_bhist(const float* __restrict__ x,
                                                     __half* __restrict__ xT,
                                                     const int2* __restrict__ idx2,
                                                     int* __restrict__ bhist) {
    int b = blockIdx.x;
    if (b < TRANS_BLOCKS) {
        int tid = b * 256 + threadIdx.x;
        if (tid < N_IN * T_DIM) {
            int col = tid >> 6, t = tid & 63;
            xT[tid] = __float2half(x[t * N_IN + col]);
        }
        return;
    }
    __shared__ int lh[NBUCK];
    int t = threadIdx.x;
    for (int i = t; i < NBUCK; i += 256) lh[i] = 0;
    __syncthreads();
    int base = (b - TRANS_BLOCKS) * HEPB;
    int end = min(base + HEPB, NNZ_E);
    for (int i = base + t; i < end; i += 256)
        atomicAdd(&lh[(unsigned)idx2[i].x >> 8], 1);
    __syncthreads();
    for (int i = t; i < NBUCK; i += 256)
        if (lh[i]) atomicAdd(&bhist[i], lh[i]);
}

// ---- tiny scan over buckets ----
__global__ void k_bscan(const int* __restrict__ bhist, int* __restrict__ bbase,
                        int* __restrict__ gcur) {
    __shared__ int buf[256];
    int t = threadIdx.x;
    int v = (t < NBUCK) ? bhist[t] : 0;
    buf[t] = v;
    __syncthreads();
    for (int off = 1; off < 256; off <<= 1) {
        int u = (t >= off) ? buf[t - off] : 0;
        __syncthreads();
        buf[t] += u;
        __syncthreads();
    }
    if (t <= NBUCK) bbase[t] = buf[t] - v;
    if (t < NBUCK)  gcur[t] = buf[t] - v;
}

// ---- pass 1: 2-pass tiny-LDS bucket binning with direct global stores ----
// rec1 record: x = col(15b) | sid<<15 (4b) | row_low<<19 (8b) ; y = weight bits
__global__ __launch_bounds__(256) void k_split(const int2* __restrict__ idx2,
                                               const float* __restrict__ iw,
                                               const int* __restrict__ sid,
                                               int* __restrict__ gcur,
                                               uint2* __restrict__ rec1) {
    __shared__ int lhist[NBUCK];
    __shared__ int lbase[NBUCK];
    int t = threadIdx.x;
    for (int i = t; i < NBUCK; i += 256) lhist[i] = 0;
    __syncthreads();
    int base = blockIdx.x * EPB;
    int n = min(EPB, NNZ_E - base);
    for (int i = t; i < n; i += 256)
        atomicAdd(&lhist[(unsigned)idx2[base + i].x >> 8], 1);
    __syncthreads();
    for (int i = t; i < NBUCK; i += 256) {
        int v = lhist[i];
        lbase[i] = v ? atomicAdd(&gcur[i], v) : 0;
        lhist[i] = 0;                     // reuse as running cursor
    }
    __syncthreads();
    for (int i = t; i < n; i += 256) {
        int2 rc = idx2[base + i];
        unsigned b = (unsigned)rc.x >> 8;
        int pos = lbase[b] + atomicAdd(&lhist[b], 1);
        unsigned x = (unsigned)rc.y | ((unsigned)sid[base + i] << 15)
                   | ((unsigned)(rc.x & 255) << 19);
        rec1[pos] = make_uint2(x, __float_as_uint(iw[base + i]));
    }
}

// ---- pass 2: per-bucket fine sort by row; 16B fp16 pre-scaled records,
//      row lists PADDED to multiples of 4 with zero records; col stored <<7 ----
__global__ __launch_bounds__(256) void k_fine(const uint2* __restrict__ rec1,
                                              const int* __restrict__ bbase,
                                              const float* __restrict__ S,
                                              uint4* __restrict__ rec,
                                              int* __restrict__ rstart,
                                              int* __restrict__ plen) {
    __shared__ int lhist[BROWS];
    __shared__ int lsc[BROWS];
    __shared__ int lcur[BROWS];
    __shared__ float s_S[NT_DIM * R_DIM];
    int t = threadIdx.x;
    if (t < NT_DIM * R_DIM) s_S[t] = S[t];
    int b = blockIdx.x;
    int s0 = bbase[b], s1 = bbase[b + 1];
    int pbase = s0 + b * PADCAP;
    lhist[t] = 0;
    __syncthreads();
    for (int i = s0 + t; i < s1; i += 256)
        atomicAdd(&lhist[(rec1[i].x >> 19) & 255], 1);
    __syncthreads();
    int v = lhist[t];
    int vp = (v + 3) & ~3;
    lsc[t] = vp;
    __syncthreads();
    for (int off = 1; off < 256; off <<= 1) {
        int u = (t >= off) ? lsc[t - off] : 0;
        __syncthreads();
        lsc[t] += u;
        __syncthreads();
    }
    int exclp = lsc[t] - vp;
    int p = b * BROWS + t;
    if (p < N_POST) { rstart[p] = pbase + exclp; plen[p] = vp; }
    lcur[t] = exclp;
    __syncthreads();
    for (int i = s0 + t; i < s1; i += 256) {
        uint2 rc = rec1[i];
        int r = (rc.x >> 19) & 255;
        int pos = atomicAdd(&lcur[r], 1);
        unsigned col = rc.x & 0x7FFF;
        const float* f = &s_S[((rc.x >> 15) & 0xF) * R_DIM];
        float w = __uint_as_float(rc.y);
        uint4 r4;
        r4.x = col << 7;                 // byte offset into fp16 xT
        r4.y = pack2h(w * f[0], w * f[1]);
        r4.z = pack2h(w * f[2], w * f[3]);
        r4.w = pack2h(w * f[4], 0.f);
        rec[pbase + pos] = r4;
    }
    for (int u = v; u < vp; ++u)
        rec[pbase + exclp + u] = make_uint4(0, 0, 0, 0);
}

// gather: byte-offset addressing (record holds col*128)
#define GX(A) (*(const __half*)(xb + ((A).x + lane2)))

#define FMA5(A, xh, c0, c1, c2, c3, c4)                  \
    do {                                                 \
        float xv_ = __half2float(xh);                    \
        float2 f01_ = uph2((A).y);                       \
        float2 f23_ = uph2((A).z);                       \
        float2 f4_  = uph2((A).w);                       \
        c0 = fmaf(xv_, f01_.x, c0);                      \
        c1 = fmaf(xv_, f01_.y, c1);                      \
        c2 = fmaf(xv_, f23_.x, c2);                      \
        c3 = fmaf(xv_, f23_.y, c3);                      \
        c4 = fmaf(xv_, f4_.x,  c4);                      \
    } while (0)

// ---- phase2: 16 rows/block; each wave runs TWO independent row-chains,
//      4-deep pipeline each; rows pre-padded to multiples of 4 (no tails) ----
__global__ __launch_bounds__(256) void k_phase2(
        const __half* __restrict__ xT, const int* __restrict__ rstart,
        const int* __restrict__ plen, const uint4* __restrict__ rec,
        float* __restrict__ out) {
    __shared__ float o_lds[T_DIM * 81];
    const char* xb = (const char*)xT;
    int tid = threadIdx.x;
    int wave = tid >> 6, lane = tid & 63;
    int lane2 = lane * 2;
    #pragma unroll
    for (int h = 0; h < 2; ++h) {
        int pa = blockIdx.x * 16 + wave * 4 + h * 2;
        int pb = pa + 1;
        int ia = __builtin_amdgcn_readfirstlane(rstart[pa]);
        int na = __builtin_amdgcn_readfirstlane(plen[pa]);
        int ib = __builtin_amdgcn_readfirstlane(rstart[pb]);
        int nb = __builtin_amdgcn_readfirstlane(plen[pb]);
        const uint4* ra = rec + ia;
        const uint4* rb = rec + ib;
        float aa0 = 0.f, aa1 = 0.f, aa2 = 0.f, aa3 = 0.f, aa4 = 0.f;
        float ab0 = 0.f, ab1 = 0.f, ab2 = 0.f, ab3 = 0.f, ab4 = 0.f;
        uint4 A0, A1, A2, A3, B0, B1, B2, B3;
        __half xa0, xa1, xa2, xa3, xb0, xb1, xb2, xb3;
        int ja = 0, jb = 0;
        if (na) {
            A0 = ra[0]; A1 = ra[1]; A2 = ra[2]; A3 = ra[3];
            xa0 = GX(A0); xa1 = GX(A1); xa2 = GX(A2); xa3 = GX(A3);
            ja = 4;
        }
        if (nb) {
            B0 = rb[0]; B1 = rb[1]; B2 = rb[2]; B3 = rb[3];
            xb0 = GX(B0); xb1 = GX(B1); xb2 = GX(B2); xb3 = GX(B3);
            jb = 4;
        }
        while (ja < na && jb < nb) {            // both chains live
            const uint4* qa = ra + ja;
            const uint4* qb = rb + jb;
            uint4 D0 = qa[0], D1 = qa[1], D2 = qa[2], D3 = qa[3];
            uint4 E0 = qb[0], E1 = qb[1], E2 = qb[2], E3 = qb[3];
            __half ya0 = GX(D0), ya1 = GX(D1), ya2 = GX(D2), ya3 = GX(D3);
            __half yb0 = GX(E0), yb1 = GX(E1), yb2 = GX(E2), yb3 = GX(E3);
            FMA5(A0, xa0, aa0, aa1, aa2, aa3, aa4);
            FMA5(A1, xa1, aa0, aa1, aa2, aa3, aa4);
            FMA5(A2, xa2, aa0, aa1, aa2, aa3, aa4);
            FMA5(A3, xa3, aa0, aa1, aa2, aa3, aa4);
            FMA5(B0, xb0, ab0, ab1, ab2, ab3, ab4);
            FMA5(B1, xb1, ab0, ab1, ab2, ab3, ab4);
            FMA5(B2, xb2, ab0, ab1, ab2, ab3, ab4);
            FMA5(B3, xb3, ab0, ab1, ab2, ab3, ab4);
            A0 = D0; A1 = D1; A2 = D2; A3 = D3;
            B0 = E0; B1 = E1; B2 = E2; B3 = E3;
            xa0 = ya0; xa1 = ya1; xa2 = ya2; xa3 = ya3;
            xb0 = yb0; xb1 = yb1; xb2 = yb2; xb3 = yb3;
            ja += 4; jb += 4;
        }
        while (ja < na) {                       // drain chain A
            const uint4* qa = ra + ja;
            uint4 D0 = qa[0], D1 = qa[1], D2 = qa[2], D3 = qa[3];
            __half ya0 = GX(D0), ya1 = GX(D1), ya2 = GX(D2), ya3 = GX(D3);
            FMA5(A0, xa0, aa0, aa1, aa2, aa3, aa4);
            FMA5(A1, xa1, aa0, aa1, aa2, aa3, aa4);
            FMA5(A2, xa2, aa0, aa1, aa2, aa3, aa4);
            FMA5(A3, xa3, aa0, aa1, aa2, aa3, aa4);
            A0 = D0; A1 = D1; A2 = D2; A3 = D3;
            xa0 = ya0; xa1 = ya1; xa2 = ya2; xa3 = ya3;
            ja += 4;
        }
        while (jb < nb) {                       // drain chain B
            const uint4* qb = rb + jb;
            uint4 E0 = qb[0], E1 = qb[1], E2 = qb[2], E3 = qb[3];
            __half yb0 = GX(E0), yb1 = GX(E1), yb2 = GX(E2), yb3 = GX(E3);
            FMA5(B0, xb0, ab0, ab1, ab2, ab3, ab4);
            FMA5(B1, xb1, ab0, ab1, ab2, ab3, ab4);
            FMA5(B2, xb2, ab0, ab1, ab2, ab3, ab4);
            FMA5(B3, xb3, ab0, ab1, ab2, ab3, ab4);
            B0 = E0; B1 = E1; B2 = E2; B3 = E3;
            xb0 = yb0; xb1 = yb1; xb2 = yb2; xb3 = yb3;
            jb += 4;
        }
        if (na) {
            FMA5(A0, xa0, aa0, aa1, aa2, aa3, aa4);
            FMA5(A1, xa1, aa0, aa1, aa2, aa3, aa4);
            FMA5(A2, xa2, aa0, aa1, aa2, aa3, aa4);
            FMA5(A3, xa3, aa0, aa1, aa2, aa3, aa4);
        }
        if (nb) {
            FMA5(B0, xb0, ab0, ab1, ab2, ab3, ab4);
            FMA5(B1, xb1, ab0, ab1, ab2, ab3, ab4);
            FMA5(B2, xb2, ab0, ab1, ab2, ab3, ab4);
            FMA5(B3, xb3, ab0, ab1, ab2, ab3, ab4);
        }
        float* da = &o_lds[lane * 81 + (wave * 4 + h * 2) * 5];
        da[0] = aa0; da[1] = aa1; da[2] = aa2; da[3] = aa3; da[4] = aa4;
        float* db = &o_lds[lane * 81 + (wave * 4 + h * 2 + 1) * 5];
        db[0] = ab0; db[1] = ab1; db[2] = ab2; db[3] = ab3; db[4] = ab4;
    }
    __syncthreads();
    int base5 = blockIdx.x * 80;
    for (int i2 = tid; i2 < T_DIM * 80; i2 += 256) {
        int t = i2 / 80;
        int j = i2 - t * 80;
        out[(size_t)t * (N_POST * R_DIM) + base5 + j] = o_lds[t * 81 + j];
    }
}

extern "C" void kernel_launch(void* const* d_in, const int* in_sizes, int n_in,
                              void* d_out, int out_size, void* d_ws, size_t ws_size,
                              hipStream_t stream) {
    const float* inp  = (const float*)d_in[0];
    const int2*  idx2 = (const int2*)d_in[1];
    const float* iw   = (const float*)d_in[2];
    const float* S    = (const float*)d_in[3];
    const int*   sid  = (const int*)d_in[4];
    float* out = (float*)d_out;

    char* ws = (char*)d_ws;
    size_t off = 0;
    auto alloc = [&](size_t bytes) -> void* {
        void* p = ws + off;
        off += (bytes + 255) & ~(size_t)255;
        return p;
    };
    __half* xT       = (__half*)alloc((size_t)N_IN * T_DIM * 2);
    int*   bhist     = (int*)alloc((size_t)NBUCK * 4);
    int*   bbase     = (int*)alloc((size_t)(NBUCK + 1) * 4);
    int*   gcur      = (int*)alloc((size_t)NBUCK * 4);
    int*   rstart    = (int*)alloc((size_t)N_POST * 4);
    int*   plen      = (int*)alloc((size_t)N_POST * 4);
    uint2* rec1      = (uint2*)alloc((size_t)NNZ_E * 8);
    uint4* rec       = (uint4*)alloc(((size_t)NNZ_E + (size_t)NBUCK * PADCAP) * 16);

    hipMemsetAsync(bhist, 0, NBUCK * 4, stream);
    k_trans_bhist<<<TRANS_BLOCKS + NBLKH, 256, 0, stream>>>(inp, xT, idx2, bhist);
    k_bscan<<<1, 256, 0, stream>>>(bhist, bbase, gcur);
    k_split<<<NBLK1, 256, 0, stream>>>(idx2, iw, sid, gcur, rec1);
    k_fine<<<NBUCK, 256, 0, stream>>>(rec1, bbase, S, rec, rstart, plen);
    k_phase2<<<N_POST / 16, 256, 0, stream>>>(xT, rstart, plen, rec, out);
}